// Round 1
// baseline (166.412 us; speedup 1.0000x reference)
//
#include <hip/hip_runtime.h>
#include <stdint.h>

// Problem constants
#define B_  1024
#define D_  512
#define K_  255
#define L_  256
#define C_  80

typedef __attribute__((ext_vector_type(8))) short bf16x8;
typedef __attribute__((ext_vector_type(4))) float f32x4;
typedef __attribute__((ext_vector_type(8))) short short8;

// async global->LDS, 16B per lane; dst must be wave-uniform base + lane*16.
#define GLD(gsrc, ldst) \
  __builtin_amdgcn_global_load_lds((const __attribute__((address_space(1))) void*)(gsrc), \
                                   (__attribute__((address_space(3))) void*)(ldst), 16, 0, 0)

__device__ __forceinline__ short cvt_bf16(float f) {
    unsigned u = __float_as_uint(f);
    u += 0x7FFFu + ((u >> 16) & 1u);
    return (short)(u >> 16);
}

// ---------------------------------------------------------------------------
// Kernel 1: convert W (20480x512) + x (1024x512) fp32->bf16, AND normalize
// ne rows -> bf16 neb (256 rows; row 255 zeroed).  Memory-bound (~66 MB).
// ---------------------------------------------------------------------------
__global__ __launch_bounds__(256) void convert_kernel(const float* __restrict__ w,
                                                      const float* __restrict__ x,
                                                      const float* __restrict__ ne,
                                                      short* __restrict__ wb,
                                                      short* __restrict__ xb,
                                                      short* __restrict__ neb) {
    __shared__ float red[256];
    const int tid = threadIdx.x;
    if (blockIdx.x < 2048) {
        size_t i0 = (size_t)blockIdx.x * 256 + tid;
        const size_t stride = 2048u * 256u;
        for (size_t v = i0; v < 1310720u; v += stride) {
            float4 a = ((const float4*)w)[v * 2];
            float4 b = ((const float4*)w)[v * 2 + 1];
            short8 o;
            o[0] = cvt_bf16(a.x); o[1] = cvt_bf16(a.y); o[2] = cvt_bf16(a.z); o[3] = cvt_bf16(a.w);
            o[4] = cvt_bf16(b.x); o[5] = cvt_bf16(b.y); o[6] = cvt_bf16(b.z); o[7] = cvt_bf16(b.w);
            ((short8*)wb)[v] = o;
        }
        for (size_t v = i0; v < 65536u; v += stride) {
            float4 a = ((const float4*)x)[v * 2];
            float4 b = ((const float4*)x)[v * 2 + 1];
            short8 o;
            o[0] = cvt_bf16(a.x); o[1] = cvt_bf16(a.y); o[2] = cvt_bf16(a.z); o[3] = cvt_bf16(a.w);
            o[4] = cvt_bf16(b.x); o[5] = cvt_bf16(b.y); o[6] = cvt_bf16(b.z); o[7] = cvt_bf16(b.w);
            ((short8*)xb)[v] = o;
        }
    } else {
        const int row = blockIdx.x - 2048;  // 0..255
        if (row == 255) {
            ((unsigned*)(neb + 255 * 512))[tid] = 0u;  // pad row = zeros
            return;
        }
        const float2* nr = (const float2*)(ne + (size_t)row * 512);
        float2 a = nr[tid];
        red[tid] = a.x * a.x + a.y * a.y;
        __syncthreads();
        #pragma unroll
        for (int s = 128; s > 0; s >>= 1) {
            if (tid < s) red[tid] += red[tid + s];
            __syncthreads();
        }
        float inv = rsqrtf(red[0]);
        unsigned lo = (unsigned short)cvt_bf16(a.x * inv);
        unsigned hi = (unsigned short)cvt_bf16(a.y * inv);
        ((unsigned*)(neb + (size_t)row * 512))[tid] = lo | (hi << 16);
    }
}

// ---------------------------------------------------------------------------
// Kernel 2: sim GEMM: out1[b,k] = sigmoid(xb[b,:]·neb[k,:]). 64x64 tiles.
// ---------------------------------------------------------------------------
__global__ __launch_bounds__(256) void simgemm_kernel(const short* __restrict__ xb,
                                                      const short* __restrict__ neb,
                                                      float* __restrict__ out1) {
    __shared__ __align__(16) short Ald[512 * 8];
    __shared__ __align__(16) short Bld[512 * 8];
    const int tid = threadIdx.x;
    const int lane = tid & 63, wave = tid >> 6;
    const int q = lane >> 4, r = lane & 15;
    const int mt = blockIdx.x >> 2;
    const int nt = blockIdx.x & 3;

    f32x4 acc[4];
    #pragma unroll
    for (int nf = 0; nf < 4; ++nf) acc[nf] = (f32x4){0.f, 0.f, 0.f, 0.f};

    const bf16x8* Av = (const bf16x8*)Ald;
    const bf16x8* Bv = (const bf16x8*)Bld;

    for (int kb = 0; kb < 8; ++kb) {
        __syncthreads();
        #pragma unroll
        for (int j = 0; j < 2; ++j) {
            int ph = j * 256 + tid, rr = ph >> 3, g = (ph & 7) ^ (rr & 7);
            GLD(xb + ((size_t)(mt * 64 + rr) * D_ + kb * 64 + g * 8), Ald + ph * 8);
        }
        #pragma unroll
        for (int j = 0; j < 2; ++j) {
            int ph = j * 256 + tid, cc = ph >> 3, g = (ph & 7) ^ (cc & 7);
            GLD(neb + ((size_t)(nt * 64 + cc) * D_ + kb * 64 + g * 8), Bld + ph * 8);
        }
        __syncthreads();
        #pragma unroll
        for (int ks = 0; ks < 2; ++ks) {
            const int g = ks * 4 + q;
            int rl = wave * 16 + r;
            bf16x8 af = Av[rl * 8 + (g ^ (rl & 7))];
            #pragma unroll
            for (int nf = 0; nf < 4; ++nf) {
                int cl = nf * 16 + r;
                bf16x8 bfr = Bv[cl * 8 + (g ^ (cl & 7))];
                acc[nf] = __builtin_amdgcn_mfma_f32_16x16x32_bf16(af, bfr, acc[nf], 0, 0, 0);
            }
        }
    }
    #pragma unroll
    for (int nf = 0; nf < 4; ++nf) {
        int gcol = nt * 64 + nf * 16 + r;
        if (gcol < K_) {
            #pragma unroll
            for (int i = 0; i < 4; ++i) {
                int grow = mt * 64 + wave * 16 + q * 4 + i;
                out1[(size_t)grow * K_ + gcol] = 1.f / (1.f + __expf(-acc[nf][i]));
            }
        }
    }
}

// ---------------------------------------------------------------------------
// Kernel 3: leaf probabilities from out1 sigmoids. Block = batch row.
// Also zeroes out0 (this kernel runs before gemm; gemm/reduce atomicAdd it).
// ---------------------------------------------------------------------------
__global__ __launch_bounds__(256) void leafprob_kernel(const float* __restrict__ out1,
                                                       float* __restrict__ p_ws,
                                                       float* __restrict__ out0) {
    __shared__ float ss[K_];
    const int b = blockIdx.x, t = threadIdx.x;
    if (t < K_) ss[t] = out1[(size_t)b * K_ + t];
    if (t < C_) out0[(size_t)b * C_ + t] = 0.f;   // zero-init for reduce atomics
    __syncthreads();
    float prob = 1.f;
    int node = 0;
    #pragma unroll
    for (int d = 0; d < 8; ++d) {
        int bit = (t >> (7 - d)) & 1;
        float s = ss[node];
        prob *= bit ? (1.f - s) : s;
        node = 2 * node + 1 + bit;
    }
    p_ws[(size_t)b * L_ + t] = prob;
}

// ---------------------------------------------------------------------------
// Kernel 4: main GEMM, restructured (round N+1):
//   - kc-outer (8 chunks of K=64), li-inner (4 leaves): A staged ONCE
//     (128 KB/block, was 512 KB), B staged minimally (320 KB/block).
//   - p-fold is linear, so fold per (li,kc) chunk: outacc += p*dec_chunk.
//     Bias folded once into outacc init (out += sum_li p*bias).
//   - Double-buffered A (2x16 KB) and B (2x10 KB) chunks; ONE barrier per
//     region; stage for region r+1 issued BEFORE computing region r, so the
//     vmcnt(0) drain at the barrier waits on loads that overlapped 20 MFMAs
//     + 14 ds_read_b128 (T3 minimal 2-phase; never a bare drain in steady
//     state). 32 regions/block, no A-boundary stalls.
//   - p/bias in registers (16-lane-broadcast loads), no p_ld/b_ld LDS.
//   - LDS 52 KB -> 2 blocks/CU at __launch_bounds__(256,2) (proven no-spill
//     register shape: outacc 40 + dec 40 + pv 32 + frags 28 ≈ 180 VGPR).
// Grid = mt(8) x lc(64) = 512 blocks; blockIdx%8 = lc%8 so the 8 m-tiles
// sharing a B slab stay co-resident on one XCD (L2 reuse).
// ---------------------------------------------------------------------------
__global__ __launch_bounds__(256, 2) void gemm_kernel(const short* __restrict__ xb,
                                                      const short* __restrict__ wb,
                                                      const float* __restrict__ p,
                                                      const float* __restrict__ lb,
                                                      float* __restrict__ partial) {
    __shared__ __align__(16) short Ald[2 * 1024 * 8];  // 2 x (128 rows x 8 granules) = 32 KB
    __shared__ __align__(16) short Bld[2 * 640 * 8];   // 2 x ( 80 rows x 8 granules) = 20 KB

    const int tid = threadIdx.x;
    const int lane = tid & 63, wave = tid >> 6;
    const int q = lane >> 4, r = lane & 15;
    const int wrow = wave * 32;
    const int lc = blockIdx.x & 63;   // 64 l-chunks of 4 leaves
    const int mt = blockIdx.x >> 6;   // 8 m-tiles of 128 rows

    // per-thread leaf probabilities pv[mf][i][li] (16-lane broadcast loads)
    float pv[2][4][4];
    #pragma unroll
    for (int mf = 0; mf < 2; ++mf)
        #pragma unroll
        for (int i = 0; i < 4; ++i) {
            int row = mt * 128 + wrow + mf * 16 + q * 4 + i;
            float4 pw = *(const float4*)(p + (size_t)row * L_ + lc * 4);
            pv[mf][i][0] = pw.x; pv[mf][i][1] = pw.y;
            pv[mf][i][2] = pw.z; pv[mf][i][3] = pw.w;
        }

    // outacc init = bias term: sum_li pv * lb[(lc*4+li)*80 + col]
    f32x4 outacc[2][5];
    #pragma unroll
    for (int nf = 0; nf < 5; ++nf) {
        float bv[4];
        #pragma unroll
        for (int li = 0; li < 4; ++li)
            bv[li] = lb[(size_t)(lc * 4 + li) * C_ + nf * 16 + r];
        #pragma unroll
        for (int mf = 0; mf < 2; ++mf)
            #pragma unroll
            for (int i = 0; i < 4; ++i)
                outacc[mf][nf][i] = pv[mf][i][0] * bv[0] + pv[mf][i][1] * bv[1]
                                  + pv[mf][i][2] * bv[2] + pv[mf][i][3] * bv[3];
    }

    // stage helpers: A chunk = 128 rows x 64 K (1024 granules, 4/thread);
    // B chunk = 80 rows x 64 K (640 granules, 2.5/thread). XOR-swizzle over
    // the 8 granules of each 128 B row (g ^ row&7) -> conflict-free ds_read.
    auto stageA = [&](int buf, int kc) {
        #pragma unroll
        for (int j = 0; j < 4; ++j) {
            int ph = j * 256 + tid;
            int rr = ph >> 3;
            int g  = (ph & 7) ^ (rr & 7);
            GLD(xb + ((size_t)(mt * 128 + rr)) * D_ + kc * 64 + g * 8,
                Ald + (buf * 1024 + ph) * 8);
        }
    };
    auto stageB = [&](int buf, int li, int kc) {
        #pragma unroll
        for (int j = 0; j < 2; ++j) {
            int ph = j * 256 + tid;
            int cc = ph >> 3;
            int g  = (ph & 7) ^ (cc & 7);
            GLD(wb + ((size_t)(lc * 4 + li) * C_ + cc) * D_ + kc * 64 + g * 8,
                Bld + (buf * 640 + ph) * 8);
        }
        if (tid < 128) {
            int ph = 512 + tid;
            int cc = ph >> 3;
            int g  = (ph & 7) ^ (cc & 7);
            GLD(wb + ((size_t)(lc * 4 + li) * C_ + cc) * D_ + kc * 64 + g * 8,
                Bld + (buf * 640 + ph) * 8);
        }
    };

    const f32x4 z4 = {0.f, 0.f, 0.f, 0.f};  // shared MFMA C-init (no per-region movs)

    int abuf = 0, bbuf = 0;
    stageA(0, 0);
    stageB(0, 0, 0);
    __syncthreads();  // compiler drains vmcnt(0) here: prologue tiles ready

    for (int kc = 0; kc < 8; ++kc) {
        #pragma unroll
        for (int li = 0; li < 4; ++li) {
            // issue next region's stage BEFORE computing this one (depth-1 prefetch)
            if (li < 3) {
                stageB(bbuf ^ 1, li + 1, kc);
            } else if (kc < 7) {
                stageB(bbuf ^ 1, 0, kc + 1);
                stageA(abuf ^ 1, kc + 1);
            }

            const bf16x8* Av = (const bf16x8*)Ald + abuf * 1024;
            const bf16x8* Bv = (const bf16x8*)Bld + bbuf * 640;

            f32x4 dec[2][5];
            #pragma unroll
            for (int ks = 0; ks < 2; ++ks) {
                const int g = ks * 4 + q;
                bf16x8 af[2], bfr[5];
                #pragma unroll
                for (int mf = 0; mf < 2; ++mf) {
                    int rl = wrow + mf * 16 + r;
                    af[mf] = Av[rl * 8 + (g ^ (rl & 7))];
                }
                #pragma unroll
                for (int nf = 0; nf < 5; ++nf) {
                    int cl = nf * 16 + r;
                    bfr[nf] = Bv[cl * 8 + (g ^ (cl & 7))];
                }
                #pragma unroll
                for (int mf = 0; mf < 2; ++mf)
                    #pragma unroll
                    for (int nf = 0; nf < 5; ++nf)
                        dec[mf][nf] = __builtin_amdgcn_mfma_f32_16x16x32_bf16(
                            af[mf], bfr[nf], ks == 0 ? z4 : dec[mf][nf], 0, 0, 0);
            }

            // linear p-fold of this K=64 chunk
            #pragma unroll
            for (int mf = 0; mf < 2; ++mf)
                #pragma unroll
                for (int nf = 0; nf < 5; ++nf)
                    #pragma unroll
                    for (int i = 0; i < 4; ++i)
                        outacc[mf][nf][i] += pv[mf][i][li] * dec[mf][nf][i];

            __syncthreads();  // drains vmcnt(0): r+1's tiles (issued above) ready
            bbuf ^= 1;
            if (li == 3) abuf ^= 1;
        }
    }

    // store partials: partial[lc][1024 rows][80 cols], this block owns 128 rows
    const size_t rbase = (size_t)lc * B_ + mt * 128;
    #pragma unroll
    for (int mf = 0; mf < 2; ++mf)
        #pragma unroll
        for (int nf = 0; nf < 5; ++nf)
            #pragma unroll
            for (int i = 0; i < 4; ++i) {
                int row = wrow + mf * 16 + q * 4 + i;
                int col = nf * 16 + r;
                partial[(rbase + row) * C_ + col] = outacc[mf][nf][i];
            }
}

// ---------------------------------------------------------------------------
// Kernel 5: reduce 64 lc partials -> out0 (1024x80).
// Grid 640 = 80 idx-chunks x 8 j-groups: each thread sums 8 slabs and
// atomicAdds (fire-and-forget f32 adds; out0 zeroed by leafprob). 8x more
// blocks than before -> full occupancy on the 21 MB stream.
// ---------------------------------------------------------------------------
__global__ __launch_bounds__(256) void reduce_kernel(const float* __restrict__ partial,
                                                     float* __restrict__ out0) {
    const int chunk = blockIdx.x >> 3;          // 0..79
    const int jg    = blockIdx.x & 7;           // 0..7
    const int idx   = chunk * 256 + threadIdx.x;  // float4 index < 20480
    const float4* p4 = (const float4*)partial;
    float4 s = {0.f, 0.f, 0.f, 0.f};
    #pragma unroll
    for (int j = 0; j < 8; ++j) {
        float4 v = p4[(size_t)(jg * 8 + j) * (B_ * C_ / 4) + idx];
        s.x += v.x; s.y += v.y; s.z += v.z; s.w += v.w;
    }
    float* o = out0 + (size_t)idx * 4;
    atomicAdd(o + 0, s.x);
    atomicAdd(o + 1, s.y);
    atomicAdd(o + 2, s.z);
    atomicAdd(o + 3, s.w);
}

// ---------------------------------------------------------------------------
extern "C" void kernel_launch(void* const* d_in, const int* in_sizes, int n_in,
                              void* d_out, int out_size, void* d_ws, size_t ws_size,
                              hipStream_t stream) {
    const float* x  = (const float*)d_in[0];  // 1024x512
    const float* ne = (const float*)d_in[1];  // 255x512
    const float* lW = (const float*)d_in[2];  // 20480x512
    const float* lb = (const float*)d_in[3];  // 20480
    // d_in[4] res_path: deterministic structure, traversed directly

    float* out0 = (float*)d_out;            // 1024x80
    float* out1 = out0 + (size_t)B_ * C_;   // 1024x255

    char* ws = (char*)d_ws;
    short* xb      = (short*)ws;                             // 1 MB
    short* neb     = (short*)(ws + (1u << 20));              // 256 KB
    float* p_ws    = (float*)(ws + (1u << 20) + (1u << 18)); // 1 MB
    short* wb      = (short*)(ws + (9u << 18));              // 20 MB @ 2.25 MB
    float* partial = (float*)(ws + (24u << 20));             // 21 MB (64x1024x80)

    convert_kernel<<<2304, 256, 0, stream>>>(lW, x, ne, wb, xb, neb);
    simgemm_kernel<<<64, 256, 0, stream>>>(xb, neb, out1);
    leafprob_kernel<<<B_, 256, 0, stream>>>(out1, p_ws, out0);
    gemm_kernel<<<512, 256, 0, stream>>>(xb, wb, p_ws, lb, partial);
    reduce_kernel<<<640, 256, 0, stream>>>(partial, out0);
}

// Round 2
// 155.443 us; speedup vs baseline: 1.0706x; 1.0706x over previous
//
#include <hip/hip_runtime.h>
#include <stdint.h>

// Problem constants
#define B_  1024
#define D_  512
#define K_  255
#define L_  256
#define C_  80

typedef __attribute__((ext_vector_type(8))) short bf16x8;
typedef __attribute__((ext_vector_type(4))) float f32x4;
typedef __attribute__((ext_vector_type(8))) short short8;

// async global->LDS, 16B per lane; dst must be wave-uniform base + lane*16.
#define GLD(gsrc, ldst) \
  __builtin_amdgcn_global_load_lds((const __attribute__((address_space(1))) void*)(gsrc), \
                                   (__attribute__((address_space(3))) void*)(ldst), 16, 0, 0)

__device__ __forceinline__ short cvt_bf16(float f) {
    unsigned u = __float_as_uint(f);
    u += 0x7FFFu + ((u >> 16) & 1u);
    return (short)(u >> 16);
}

// ---------------------------------------------------------------------------
// Kernel 1: convert W (20480x512) + x (1024x512) fp32->bf16, AND normalize
// ne rows -> bf16 neb (256 rows; row 255 zeroed).  Memory-bound (~66 MB).
// ---------------------------------------------------------------------------
__global__ __launch_bounds__(256) void convert_kernel(const float* __restrict__ w,
                                                      const float* __restrict__ x,
                                                      const float* __restrict__ ne,
                                                      short* __restrict__ wb,
                                                      short* __restrict__ xb,
                                                      short* __restrict__ neb) {
    __shared__ float red[256];
    const int tid = threadIdx.x;
    if (blockIdx.x < 2048) {
        size_t i0 = (size_t)blockIdx.x * 256 + tid;
        const size_t stride = 2048u * 256u;
        for (size_t v = i0; v < 1310720u; v += stride) {
            float4 a = ((const float4*)w)[v * 2];
            float4 b = ((const float4*)w)[v * 2 + 1];
            short8 o;
            o[0] = cvt_bf16(a.x); o[1] = cvt_bf16(a.y); o[2] = cvt_bf16(a.z); o[3] = cvt_bf16(a.w);
            o[4] = cvt_bf16(b.x); o[5] = cvt_bf16(b.y); o[6] = cvt_bf16(b.z); o[7] = cvt_bf16(b.w);
            ((short8*)wb)[v] = o;
        }
        for (size_t v = i0; v < 65536u; v += stride) {
            float4 a = ((const float4*)x)[v * 2];
            float4 b = ((const float4*)x)[v * 2 + 1];
            short8 o;
            o[0] = cvt_bf16(a.x); o[1] = cvt_bf16(a.y); o[2] = cvt_bf16(a.z); o[3] = cvt_bf16(a.w);
            o[4] = cvt_bf16(b.x); o[5] = cvt_bf16(b.y); o[6] = cvt_bf16(b.z); o[7] = cvt_bf16(b.w);
            ((short8*)xb)[v] = o;
        }
    } else {
        const int row = blockIdx.x - 2048;  // 0..255
        if (row == 255) {
            ((unsigned*)(neb + 255 * 512))[tid] = 0u;  // pad row = zeros
            return;
        }
        const float2* nr = (const float2*)(ne + (size_t)row * 512);
        float2 a = nr[tid];
        red[tid] = a.x * a.x + a.y * a.y;
        __syncthreads();
        #pragma unroll
        for (int s = 128; s > 0; s >>= 1) {
            if (tid < s) red[tid] += red[tid + s];
            __syncthreads();
        }
        float inv = rsqrtf(red[0]);
        unsigned lo = (unsigned short)cvt_bf16(a.x * inv);
        unsigned hi = (unsigned short)cvt_bf16(a.y * inv);
        ((unsigned*)(neb + (size_t)row * 512))[tid] = lo | (hi << 16);
    }
}

// ---------------------------------------------------------------------------
// Kernel 2: sim GEMM: out1[b,k] = sigmoid(xb[b,:]·neb[k,:]). 64x64 tiles.
// ---------------------------------------------------------------------------
__global__ __launch_bounds__(256) void simgemm_kernel(const short* __restrict__ xb,
                                                      const short* __restrict__ neb,
                                                      float* __restrict__ out1) {
    __shared__ __align__(16) short Ald[512 * 8];
    __shared__ __align__(16) short Bld[512 * 8];
    const int tid = threadIdx.x;
    const int lane = tid & 63, wave = tid >> 6;
    const int q = lane >> 4, r = lane & 15;
    const int mt = blockIdx.x >> 2;
    const int nt = blockIdx.x & 3;

    f32x4 acc[4];
    #pragma unroll
    for (int nf = 0; nf < 4; ++nf) acc[nf] = (f32x4){0.f, 0.f, 0.f, 0.f};

    const bf16x8* Av = (const bf16x8*)Ald;
    const bf16x8* Bv = (const bf16x8*)Bld;

    for (int kb = 0; kb < 8; ++kb) {
        __syncthreads();
        #pragma unroll
        for (int j = 0; j < 2; ++j) {
            int ph = j * 256 + tid, rr = ph >> 3, g = (ph & 7) ^ (rr & 7);
            GLD(xb + ((size_t)(mt * 64 + rr) * D_ + kb * 64 + g * 8), Ald + ph * 8);
        }
        #pragma unroll
        for (int j = 0; j < 2; ++j) {
            int ph = j * 256 + tid, cc = ph >> 3, g = (ph & 7) ^ (cc & 7);
            GLD(neb + ((size_t)(nt * 64 + cc) * D_ + kb * 64 + g * 8), Bld + ph * 8);
        }
        __syncthreads();
        #pragma unroll
        for (int ks = 0; ks < 2; ++ks) {
            const int g = ks * 4 + q;
            int rl = wave * 16 + r;
            bf16x8 af = Av[rl * 8 + (g ^ (rl & 7))];
            #pragma unroll
            for (int nf = 0; nf < 4; ++nf) {
                int cl = nf * 16 + r;
                bf16x8 bfr = Bv[cl * 8 + (g ^ (cl & 7))];
                acc[nf] = __builtin_amdgcn_mfma_f32_16x16x32_bf16(af, bfr, acc[nf], 0, 0, 0);
            }
        }
    }
    #pragma unroll
    for (int nf = 0; nf < 4; ++nf) {
        int gcol = nt * 64 + nf * 16 + r;
        if (gcol < K_) {
            #pragma unroll
            for (int i = 0; i < 4; ++i) {
                int grow = mt * 64 + wave * 16 + q * 4 + i;
                out1[(size_t)grow * K_ + gcol] = 1.f / (1.f + __expf(-acc[nf][i]));
            }
        }
    }
}

// ---------------------------------------------------------------------------
// Kernel 3: leaf probabilities from out1 sigmoids. Block = batch row.
// Also zeroes out0 (this kernel runs before gemm; reduce atomicAdds into it).
// ---------------------------------------------------------------------------
__global__ __launch_bounds__(256) void leafprob_kernel(const float* __restrict__ out1,
                                                       float* __restrict__ p_ws,
                                                       float* __restrict__ out0) {
    __shared__ float ss[K_];
    const int b = blockIdx.x, t = threadIdx.x;
    if (t < K_) ss[t] = out1[(size_t)b * K_ + t];
    if (t < C_) out0[(size_t)b * C_ + t] = 0.f;   // zero-init for reduce atomics
    __syncthreads();
    float prob = 1.f;
    int node = 0;
    #pragma unroll
    for (int d = 0; d < 8; ++d) {
        int bit = (t >> (7 - d)) & 1;
        float s = ss[node];
        prob *= bit ? (1.f - s) : s;
        node = 2 * node + 1 + bit;
    }
    p_ws[(size_t)b * L_ + t] = prob;
}

// ---------------------------------------------------------------------------
// Kernel 4: main GEMM.
// Round-2 theory: round-1's regression was register pressure (pv in 32 VGPRs
// on top of dec+outacc+frags -> ~160 live vs VGPR_Count=128 -> spill traffic,
// visible as ~28 MB excess WRITE_SIZE). This version keeps round-1's good
// structure (kc-outer so A staged ONCE; one barrier/region; depth-1 prefetch
// issued BEFORE compute) but restores round-0's proven register discipline:
//   - p back in LDS (p_ld[128][4], 2 KB); fold reads it per-region (the
//     __syncthreads fence stops the compiler re-hoisting it into registers).
//   - bias folded once into outacc init from LDS p + global lb.
// Peak live regs ~123 (outacc 40 + dec 40 + frags 28 + addr) = round-0 shape.
// LDS: A 2x16 KB + B 2x10 KB + p 2 KB = 54 KB -> 2 blocks/CU.
// Grid = mt(8) x lc(64) = 512 blocks; blockIdx%8 = lc%8 keeps the 8 m-tiles
// sharing a B slab on one XCD (~2.6 MB W/XCD, L2-resident).
// ---------------------------------------------------------------------------
__global__ __launch_bounds__(256, 2) void gemm_kernel(const short* __restrict__ xb,
                                                      const short* __restrict__ wb,
                                                      const float* __restrict__ p,
                                                      const float* __restrict__ lb,
                                                      float* __restrict__ partial) {
    __shared__ __align__(16) short Ald[2 * 1024 * 8];  // 2 x (128 rows x 8 granules) = 32 KB
    __shared__ __align__(16) short Bld[2 * 640 * 8];   // 2 x ( 80 rows x 8 granules) = 20 KB
    __shared__ float p_ld[128][4];                     // 2 KB

    const int tid = threadIdx.x;
    const int lane = tid & 63, wave = tid >> 6;
    const int q = lane >> 4, r = lane & 15;
    const int wrow = wave * 32;
    const int lc = blockIdx.x & 63;   // 64 l-chunks of 4 leaves
    const int mt = blockIdx.x >> 6;   // 8 m-tiles of 128 rows

    if (tid < 128) {
        float4 pw = *(const float4*)(p + (size_t)(mt * 128 + tid) * L_ + lc * 4);
        p_ld[tid][0] = pw.x; p_ld[tid][1] = pw.y;
        p_ld[tid][2] = pw.z; p_ld[tid][3] = pw.w;
    }

    // stage helpers: A chunk = 128 rows x 64 K (1024 granules, 4/thread);
    // B chunk = 80 rows x 64 K (640 granules, 2.5/thread). XOR-swizzle over
    // the 8 granules of each 128 B row (g ^ row&7) -> conflict-free ds_read.
    auto stageA = [&](int buf, int kc) {
        #pragma unroll
        for (int j = 0; j < 4; ++j) {
            int ph = j * 256 + tid;
            int rr = ph >> 3;
            int g  = (ph & 7) ^ (rr & 7);
            GLD(xb + ((size_t)(mt * 128 + rr)) * D_ + kc * 64 + g * 8,
                Ald + (buf * 1024 + ph) * 8);
        }
    };
    auto stageB = [&](int buf, int li, int kc) {
        #pragma unroll
        for (int j = 0; j < 2; ++j) {
            int ph = j * 256 + tid;
            int cc = ph >> 3;
            int g  = (ph & 7) ^ (cc & 7);
            GLD(wb + ((size_t)(lc * 4 + li) * C_ + cc) * D_ + kc * 64 + g * 8,
                Bld + (buf * 640 + ph) * 8);
        }
        if (tid < 128) {
            int ph = 512 + tid;
            int cc = ph >> 3;
            int g  = (ph & 7) ^ (cc & 7);
            GLD(wb + ((size_t)(lc * 4 + li) * C_ + cc) * D_ + kc * 64 + g * 8,
                Bld + (buf * 640 + ph) * 8);
        }
    };

    stageA(0, 0);
    stageB(0, 0, 0);
    __syncthreads();  // drains prologue GLDs; p_ld visible to all threads

    // outacc init = bias term: sum_li p_ld[row][li] * lb[(lc*4+li)*80 + col]
    f32x4 outacc[2][5];
    #pragma unroll
    for (int nf = 0; nf < 5; ++nf) {
        float bv[4];
        #pragma unroll
        for (int li = 0; li < 4; ++li)
            bv[li] = lb[(size_t)(lc * 4 + li) * C_ + nf * 16 + r];
        #pragma unroll
        for (int mf = 0; mf < 2; ++mf)
            #pragma unroll
            for (int i = 0; i < 4; ++i) {
                int row = wrow + mf * 16 + q * 4 + i;
                outacc[mf][nf][i] = p_ld[row][0] * bv[0] + p_ld[row][1] * bv[1]
                                  + p_ld[row][2] * bv[2] + p_ld[row][3] * bv[3];
            }
    }

    const f32x4 z4 = {0.f, 0.f, 0.f, 0.f};  // shared MFMA C-init

    int abuf = 0, bbuf = 0;
    for (int kc = 0; kc < 8; ++kc) {
        #pragma unroll
        for (int li = 0; li < 4; ++li) {
            // issue next region's stage BEFORE computing this one (depth-1 prefetch)
            if (li < 3) {
                stageB(bbuf ^ 1, li + 1, kc);
            } else if (kc < 7) {
                stageB(bbuf ^ 1, 0, kc + 1);
                stageA(abuf ^ 1, kc + 1);
            }

            const bf16x8* Av = (const bf16x8*)Ald + abuf * 1024;
            const bf16x8* Bv = (const bf16x8*)Bld + bbuf * 640;

            f32x4 dec[2][5];
            #pragma unroll
            for (int ks = 0; ks < 2; ++ks) {
                const int g = ks * 4 + q;
                bf16x8 af[2], bfr[5];
                #pragma unroll
                for (int mf = 0; mf < 2; ++mf) {
                    int rl = wrow + mf * 16 + r;
                    af[mf] = Av[rl * 8 + (g ^ (rl & 7))];
                }
                #pragma unroll
                for (int nf = 0; nf < 5; ++nf) {
                    int cl = nf * 16 + r;
                    bfr[nf] = Bv[cl * 8 + (g ^ (cl & 7))];
                }
                #pragma unroll
                for (int mf = 0; mf < 2; ++mf)
                    #pragma unroll
                    for (int nf = 0; nf < 5; ++nf)
                        dec[mf][nf] = __builtin_amdgcn_mfma_f32_16x16x32_bf16(
                            af[mf], bfr[nf], ks == 0 ? z4 : dec[mf][nf], 0, 0, 0);
            }

            // linear p-fold of this K=64 chunk; p read from LDS per region
            // (syncthreads fence keeps these as ds_reads, not 32 hoisted regs)
            #pragma unroll
            for (int mf = 0; mf < 2; ++mf)
                #pragma unroll
                for (int i = 0; i < 4; ++i) {
                    float pf = p_ld[wrow + mf * 16 + q * 4 + i][li];
                    #pragma unroll
                    for (int nf = 0; nf < 5; ++nf)
                        outacc[mf][nf][i] += pf * dec[mf][nf][i];
                }

            __syncthreads();  // drains vmcnt(0): next region's tiles ready
            bbuf ^= 1;
            if (li == 3) abuf ^= 1;
        }
    }

    // store partials: partial[lc][1024 rows][80 cols], this block owns 128 rows
    const size_t rbase = (size_t)lc * B_ + mt * 128;
    #pragma unroll
    for (int mf = 0; mf < 2; ++mf)
        #pragma unroll
        for (int nf = 0; nf < 5; ++nf)
            #pragma unroll
            for (int i = 0; i < 4; ++i) {
                int row = wrow + mf * 16 + q * 4 + i;
                int col = nf * 16 + r;
                partial[(rbase + row) * C_ + col] = outacc[mf][nf][i];
            }
}

// ---------------------------------------------------------------------------
// Kernel 5: reduce 64 lc partials -> out0 (1024x80).
// Grid 640 = 80 idx-chunks x 8 j-groups: each thread sums 8 slabs and
// atomicAdds (out0 zeroed by leafprob).
// ---------------------------------------------------------------------------
__global__ __launch_bounds__(256) void reduce_kernel(const float* __restrict__ partial,
                                                     float* __restrict__ out0) {
    const int chunk = blockIdx.x >> 3;            // 0..79
    const int jg    = blockIdx.x & 7;             // 0..7
    const int idx   = chunk * 256 + threadIdx.x;  // float4 index < 20480
    const float4* p4 = (const float4*)partial;
    float4 s = {0.f, 0.f, 0.f, 0.f};
    #pragma unroll
    for (int j = 0; j < 8; ++j) {
        float4 v = p4[(size_t)(jg * 8 + j) * (B_ * C_ / 4) + idx];
        s.x += v.x; s.y += v.y; s.z += v.z; s.w += v.w;
    }
    float* o = out0 + (size_t)idx * 4;
    atomicAdd(o + 0, s.x);
    atomicAdd(o + 1, s.y);
    atomicAdd(o + 2, s.z);
    atomicAdd(o + 3, s.w);
}

// ---------------------------------------------------------------------------
extern "C" void kernel_launch(void* const* d_in, const int* in_sizes, int n_in,
                              void* d_out, int out_size, void* d_ws, size_t ws_size,
                              hipStream_t stream) {
    const float* x  = (const float*)d_in[0];  // 1024x512
    const float* ne = (const float*)d_in[1];  // 255x512
    const float* lW = (const float*)d_in[2];  // 20480x512
    const float* lb = (const float*)d_in[3];  // 20480
    // d_in[4] res_path: deterministic structure, traversed directly

    float* out0 = (float*)d_out;            // 1024x80
    float* out1 = out0 + (size_t)B_ * C_;   // 1024x255

    char* ws = (char*)d_ws;
    short* xb      = (short*)ws;                             // 1 MB
    short* neb     = (short*)(ws + (1u << 20));              // 256 KB
    float* p_ws    = (float*)(ws + (1u << 20) + (1u << 18)); // 1 MB
    short* wb      = (short*)(ws + (9u << 18));              // 20 MB @ 2.25 MB
    float* partial = (float*)(ws + (24u << 20));             // 21 MB (64x1024x80)

    convert_kernel<<<2304, 256, 0, stream>>>(lW, x, ne, wb, xb, neb);
    simgemm_kernel<<<64, 256, 0, stream>>>(xb, neb, out1);
    leafprob_kernel<<<B_, 256, 0, stream>>>(out1, p_ws, out0);
    gemm_kernel<<<512, 256, 0, stream>>>(xb, wb, p_ws, lb, partial);
    reduce_kernel<<<640, 256, 0, stream>>>(partial, out0);
}